// Round 8
// baseline (1263.630 us; speedup 1.0000x reference)
//
#include <hip/hip_runtime.h>
#include <hip/hip_bf16.h>
#include <stdint.h>

typedef __bf16 bf16;
typedef __bf16 bf16x8 __attribute__((ext_vector_type(8)));
typedef float f32x4 __attribute__((ext_vector_type(4)));
typedef unsigned short u16;

constexpr int NB = 4;
constexpr int NT = 2048;
constexpr int NC = 2048;
constexpr int NH = 16;
constexpr int ND = 128;
constexpr int NC3 = 6144;

#define SWZP(row) ((((row) >> 2) << 1) | ((row) & 1))

__device__ __forceinline__ void gload16(const void* g, void* l) {
  __builtin_amdgcn_global_load_lds((const __attribute__((address_space(1))) void*)g,
                                   (__attribute__((address_space(3))) void*)l, 16, 0, 0);
}

// ---------------- ingest: f32 -> bf16, n multiple of 8 ----------------
__global__ __launch_bounds__(256) void ingest_k(const float* __restrict__ raw, bf16* __restrict__ out, long n) {
  long i = ((long)blockIdx.x * 256 + threadIdx.x) * 8;
  if (i >= n) return;
  f32x4 a = *(const f32x4*)(raw + i), b = *(const f32x4*)(raw + i + 4);
  bf16x8 o;
  o[0] = (bf16)a[0]; o[1] = (bf16)a[1]; o[2] = (bf16)a[2]; o[3] = (bf16)a[3];
  o[4] = (bf16)b[0]; o[5] = (bf16)b[1]; o[6] = (bf16)b[2]; o[7] = (bf16)b[3];
  *(bf16x8*)(out + i) = o;
}

// ---------------- mask format detect + expand to int32 (proven) ----------------
__global__ void mask_prep_k(const void* raw, int* out) {
  __shared__ int s_gt1, s_oddnz, s_allb, s_allf, s_allh;
  if (threadIdx.x == 0) { s_gt1 = 0; s_oddnz = 0; s_allb = 1; s_allf = 1; s_allh = 1; }
  __syncthreads();
  const unsigned int* mw = (const unsigned int*)raw;
  int gt1 = 0, oddnz = 0, allb = 1, allf = 1, allh = 1;
  for (int i = threadIdx.x; i < 2048; i += 256) {
    unsigned v = mw[i];
    if (v > 1u) gt1 = 1;
    if ((i & 1) && v) oddnz = 1;
#pragma unroll
    for (int bb = 0; bb < 4; ++bb) { unsigned by = (v >> (8*bb)) & 0xffu; if (by > 1u) allb = 0; }
    if (v != 0u && v != 0x3F800000u) allf = 0;
    unsigned lo = v & 0xffffu, hi = v >> 16;
    if ((lo != 0u && lo != 0x3F80u) || (hi != 0u && hi != 0x3F80u)) allh = 0;
  }
  if (gt1) atomicOr(&s_gt1, 1);
  if (oddnz) atomicOr(&s_oddnz, 1);
  if (!allb) atomicAnd(&s_allb, 0);
  if (!allf) atomicAnd(&s_allf, 0);
  if (!allh) atomicAnd(&s_allh, 0);
  __syncthreads();
  int mode;
  if (!s_gt1)       mode = s_oddnz ? 0 : 2;
  else if (s_allf)  mode = 3;
  else if (s_allb)  mode = 1;
  else if (s_allh)  mode = 4;
  else              mode = 0;
  for (int i = threadIdx.x; i < NB*NT; i += 256) {
    int v;
    if (mode == 0)      v = (((const int*)raw)[i] != 0);
    else if (mode == 1) v = (((const unsigned char*)raw)[i] != 0);
    else if (mode == 2) v = (((const long long*)raw)[i] != 0);
    else if (mode == 3) v = (((const unsigned int*)raw)[i] != 0);
    else                v = (((const unsigned short*)raw)[i] != 0);
    out[i] = v;
  }
}

// ---------------- fused transpose+cast: out[c][r] = bf16(in_f32[r][c]), 64x64 tiles ----------------
__global__ __launch_bounds__(256) void transpose_f32_k(const float* __restrict__ in, bf16* __restrict__ out,
                                                       int in_rs, int out_rs) {
  __shared__ __align__(16) bf16 t[64][72];
  const int r0 = blockIdx.y << 6, c0 = blockIdx.x << 6;
  const int tid = threadIdx.x;
#pragma unroll
  for (int i = 0; i < 4; ++i) {
    int slot = i*256 + tid, row = slot >> 4, c4 = slot & 15;
    f32x4 v = *(const f32x4*)(in + (long)(r0 + row)*in_rs + c0 + c4*4);
#pragma unroll
    for (int e = 0; e < 4; ++e) t[c4*4 + e][row] = (bf16)v[e];
  }
  __syncthreads();
#pragma unroll
  for (int i = 0; i < 2; ++i) {
    int slot = i*256 + tid, row = slot >> 3, c8 = slot & 7;
    bf16x8 v = *(const bf16x8*)(&t[row][c8*8]);
    *(bf16x8*)(out + (long)(c0 + row)*out_rs + r0 + c8*8) = v;
  }
}

// ---------------- V^T extraction: vt[(b*H+h)*128 + d][t] = qkv[b*T+t][4096 + h*128 + d] ----------------
__global__ __launch_bounds__(256) void vtrans_k(const bf16* __restrict__ qkv, bf16* __restrict__ vt) {
  __shared__ __align__(16) bf16 t[64][72];
  const int tt = blockIdx.x, dh = blockIdx.y, bh = blockIdx.z;
  const int b = bh >> 4, h = bh & 15;
  const int tid = threadIdx.x;
  const bf16* src = qkv + (long)(b*NT + tt*64)*NC3 + (2*NC + h*ND + dh*64);
#pragma unroll
  for (int i = 0; i < 2; ++i) {
    int slot = i*256 + tid, row = slot >> 3, c8 = slot & 7;
    bf16x8 v = *(const bf16x8*)(src + (long)row*NC3 + c8*8);
#pragma unroll
    for (int e = 0; e < 8; ++e) t[c8*8 + e][row] = v[e];
  }
  __syncthreads();
  bf16* dst = vt + ((long)bh*ND + dh*64)*NT + tt*64;
#pragma unroll
  for (int i = 0; i < 2; ++i) {
    int slot = i*256 + tid, row = slot >> 3, c8 = slot & 7;
    bf16x8 v = *(const bf16x8*)(&t[row][c8*8]);
    *(bf16x8*)(dst + (long)row*NT + c8*8) = v;
  }
}

// ---------------- GEMM: C[M,N] = A[M,K] * B, with BT = B^T [N,K] row-major ----------------
template <typename OT>
__global__ __launch_bounds__(256, 2) void gemm_bt_k(const bf16* __restrict__ A, const bf16* __restrict__ BT,
                                                    OT* __restrict__ Cout, int M, int N, int K) {
  const int tid = threadIdx.x, w = tid >> 6, l = tid & 63, g = l >> 4, r = l & 15;
  const int wr = w >> 1, wc = w & 1;
  const long m0 = (long)blockIdx.y << 7, n0 = (long)blockIdx.x << 7;
  __shared__ __align__(16) char As[16384];
  __shared__ __align__(16) char Bs[16384];

  long aoff[4], boff[4];
  char *al_[4], *bl_[4];
#pragma unroll
  for (int i = 0; i < 4; ++i) {
    int slot = i*256 + tid, row = slot >> 3, c = slot & 7, cp = c ^ (row & 7);
    aoff[i] = (m0 + row)*(long)K + cp*8;
    boff[i] = (n0 + row)*(long)K + cp*8;
    al_[i] = As + ((i*256 + w*64) << 4);
    bl_[i] = Bs + ((i*256 + w*64) << 4);
  }

  const f32x4 z4 = {0.f, 0.f, 0.f, 0.f};
  f32x4 acc[4][4];
#pragma unroll
  for (int mc = 0; mc < 4; ++mc)
#pragma unroll
    for (int nc = 0; nc < 4; ++nc) acc[mc][nc] = z4;

  for (int k0 = 0; k0 < K; k0 += 64) {
#pragma unroll
    for (int i = 0; i < 4; ++i) {
      gload16(A + aoff[i] + k0, al_[i]);
      gload16(BT + boff[i] + k0, bl_[i]);
    }
    __syncthreads();
#pragma unroll
    for (int kk = 0; kk < 2; ++kk) {
      bf16x8 af[4], bfr[4];
#pragma unroll
      for (int mc = 0; mc < 4; ++mc) {
        int row = wr*64 + mc*16 + r;
        af[mc] = *(const bf16x8*)(As + row*128 + (((kk*4 + g) ^ (row & 7)) << 4));
      }
#pragma unroll
      for (int nc = 0; nc < 4; ++nc) {
        int row = wc*64 + nc*16 + r;
        bfr[nc] = *(const bf16x8*)(Bs + row*128 + (((kk*4 + g) ^ (row & 7)) << 4));
      }
#pragma unroll
      for (int mc = 0; mc < 4; ++mc)
#pragma unroll
        for (int nc = 0; nc < 4; ++nc)
          acc[mc][nc] = __builtin_amdgcn_mfma_f32_16x16x32_bf16(af[mc], bfr[nc], acc[mc][nc], 0, 0, 0);
    }
    __syncthreads();
  }
#pragma unroll
  for (int mc = 0; mc < 4; ++mc)
#pragma unroll
    for (int nc = 0; nc < 4; ++nc)
#pragma unroll
      for (int j = 0; j < 4; ++j) {
        long mr = m0 + wr*64 + mc*16 + 4*g + j;
        long nc_ = n0 + wc*64 + nc*16 + r;
        Cout[mr*(long)N + nc_] = (OT)acc[mc][nc][j];
      }
}

// ---------------- fused causal+masked flash attention, QBLK=128, V direct-from-global ----------------
// block = (qx,h,b): 128 q-rows, 4 waves x 32 rows (2 chunks of 16). KVBLK=64, K double-buffered in LDS.
// LDS = 42KB -> 3 blocks/CU co-resident. V^T fragments read straight from global (L2-resident).
__global__ __launch_bounds__(256, 3) void attn_k(const bf16* __restrict__ qkv, const bf16* __restrict__ vt,
                                                 const int* __restrict__ mask, bf16* __restrict__ y) {
  const int qx = blockIdx.x, h = blockIdx.y, b = blockIdx.z;
  const int qb = (qx & 1) ? (15 - (qx >> 1)) : (qx >> 1);   // work-balance remap (bijective)
  const int tid = threadIdx.x, w = tid >> 6, l = tid & 63, g = l >> 4, r = l & 15;
  const int q0 = qb << 7;
  const int bh = b*NH + h;
  const int ntiles = (q0 + 128) >> 6;                        // 2qb+2

  __shared__ __align__(16) char Klds[2][16384];   // [64 key][128 d], swizzled 16B slots
  __shared__ __align__(16) char Plds[8192];       // per-wave [16 q][64 key] bf16 (reused per chunk)
  __shared__ char Mc[2048];                       // key mask (char) for this b
  char* Pl = Plds + (w << 11);

  for (int i = tid; i < q0 + 128; i += 256) Mc[i] = (char)(mask[b*NT + i] != 0);

  long koff[4];
  int klo[4];
#pragma unroll
  for (int i = 0; i < 4; ++i) {
    int slot = i*256 + tid;                       // K: 64 rows x 16 slots
    int row = slot >> 4, c = slot & 15, cp = c ^ (row & 7);
    koff[i] = (long)row*NC3 + cp*8;
    klo[i] = (i*256 + w*64) << 4;
  }
  const bf16* kbase0 = qkv + (long)(b*NT)*NC3 + (NC + h*ND);
  const bf16* vbase0 = vt + (long)bh*ND*NT;

  bf16x8 qf[2][4];
#pragma unroll
  for (int jj = 0; jj < 2; ++jj) {
    const int qrow = q0 + w*32 + jj*16 + r;
    const bf16* qp = qkv + (long)(b*NT + qrow)*NC3 + h*ND + g*8;
#pragma unroll
    for (int dk = 0; dk < 4; ++dk) qf[jj][dk] = *(const bf16x8*)(qp + dk*32);
  }

  const f32x4 z4 = {0.f, 0.f, 0.f, 0.f};
  f32x4 acc[2][8];
#pragma unroll
  for (int jj = 0; jj < 2; ++jj)
#pragma unroll
    for (int i = 0; i < 8; ++i) acc[jj][i] = z4;
  float m_run[2][4], l_run[2][4];
#pragma unroll
  for (int jj = 0; jj < 2; ++jj)
#pragma unroll
    for (int j = 0; j < 4; ++j) { m_run[jj][j] = -3.0e38f; l_run[jj][j] = 0.f; }

  const float SCL = 0.08838834764831845f * 1.4426950408889634f;  // 1/sqrt(128) * log2(e)

  // prologue: stage K tile 0 into buffer 0
#pragma unroll
  for (int i = 0; i < 4; ++i) gload16(kbase0 + koff[i], Klds[0] + klo[i]);
  __syncthreads();

  for (int kt = 0; kt < ntiles; ++kt) {
    const int cur = kt & 1;
    if (kt + 1 < ntiles) {
      const bf16* kb = kbase0 + (long)((kt+1)*64)*NC3;
#pragma unroll
      for (int i = 0; i < 4; ++i) gload16(kb + koff[i], Klds[cur^1] + klo[i]);
    }
    const char* Kl = Klds[cur];
    const int key0 = kt*64;
    // chunk-active flags (wave-uniform)
    const bool act1 = (key0 <= q0 + w*32 + 31);
    const bool act0 = (key0 <= q0 + w*32 + 15);

    char mvc[4];
#pragma unroll
    for (int kc = 0; kc < 4; ++kc) mvc[kc] = Mc[key0 + kc*16 + r];

    float tv[2][4][4];
    if (act1) {
      __builtin_amdgcn_s_setprio(1);
#pragma unroll
      for (int kc = 0; kc < 4; ++kc) {
        const int krow = kc*16 + r;
        bf16x8 kf[4];
#pragma unroll
        for (int dk = 0; dk < 4; ++dk)
          kf[dk] = *(const bf16x8*)(Kl + krow*256 + (((dk*4 + g) ^ (krow & 7)) << 4));
        f32x4 s0 = z4, s1 = z4;
#pragma unroll
        for (int dk = 0; dk < 4; ++dk) {
          s0 = __builtin_amdgcn_mfma_f32_16x16x32_bf16(qf[0][dk], kf[dk], s0, 0, 0, 0);
          s1 = __builtin_amdgcn_mfma_f32_16x16x32_bf16(qf[1][dk], kf[dk], s1, 0, 0, 0);
        }
        const int key = key0 + krow;
#pragma unroll
        for (int j = 0; j < 4; ++j) {
          const int qr0 = q0 + w*32 + 4*g + j;          // chunk0 row; chunk1 row = qr0+16
          tv[0][kc][j] = (mvc[kc] && key <= qr0)      ? s0[j]*SCL : -3.0e38f;
          tv[1][kc][j] = (mvc[kc] && key <= qr0 + 16) ? s1[j]*SCL : -3.0e38f;
        }
      }
      __builtin_amdgcn_s_setprio(0);
    }

    bf16x8 pa0[2], pa1[2];
#pragma unroll
    for (int jj = 0; jj < 2; ++jj) {
      const bool act = jj ? act1 : act0;
      if (act) {
        float tmax[4] = {-3.0e38f, -3.0e38f, -3.0e38f, -3.0e38f};
#pragma unroll
        for (int kc = 0; kc < 4; ++kc)
#pragma unroll
          for (int j = 0; j < 4; ++j) tmax[j] = fmaxf(tmax[j], tv[jj][kc][j]);
#pragma unroll
        for (int j = 0; j < 4; ++j) {
#pragma unroll
          for (int off = 1; off < 16; off <<= 1) tmax[j] = fmaxf(tmax[j], __shfl_xor(tmax[j], off));
        }
        float al[4], rs[4];
#pragma unroll
        for (int j = 0; j < 4; ++j) {
          float mn = fmaxf(m_run[jj][j], tmax[j]);
          al[j] = exp2f(m_run[jj][j] - mn);
          m_run[jj][j] = mn;
          rs[j] = 0.f;
        }
#pragma unroll
        for (int kc = 0; kc < 4; ++kc) {
#pragma unroll
          for (int j = 0; j < 4; ++j) {
            float p = exp2f(tv[jj][kc][j] - m_run[jj][j]);
            rs[j] += p;
            int prow = 4*g + j;
            int cb = (kc*16 + r)*2;
            int sl = (cb >> 4) ^ SWZP(prow);
            *(u16*)(Pl + prow*128 + (sl << 4) + (cb & 15)) = __builtin_bit_cast(u16, (bf16)p);
          }
        }
#pragma unroll
        for (int j = 0; j < 4; ++j) {
#pragma unroll
          for (int off = 1; off < 16; off <<= 1) rs[j] += __shfl_xor(rs[j], off);
          l_run[jj][j] = l_run[jj][j]*al[j] + rs[j];
        }
#pragma unroll
        for (int d0 = 0; d0 < 8; ++d0)
#pragma unroll
          for (int j = 0; j < 4; ++j) acc[jj][d0][j] *= al[j];
        // P write -> read fence (same-wave DS; pin hw counter + scheduler, rule #18)
        asm volatile("s_waitcnt lgkmcnt(0)" ::: "memory");
        __builtin_amdgcn_sched_barrier(0);
#pragma unroll
        for (int kk = 0; kk < 2; ++kk) {
          bf16x8 pv = *(const bf16x8*)(Pl + r*128 + (((kk*4 + g) ^ SWZP(r)) << 4));
          if (jj) pa1[kk] = pv; else pa0[kk] = pv;
        }
      }
    }

    if (act1) {
      const bf16* vb = vbase0 + key0 + g*8;
      __builtin_amdgcn_s_setprio(1);
#pragma unroll
      for (int d0 = 0; d0 < 8; ++d0) {
        const long vrow = (long)(d0*16 + r)*NT;
#pragma unroll
        for (int kk = 0; kk < 2; ++kk) {
          bf16x8 vf = *(const bf16x8*)(vb + vrow + kk*32);   // V^T direct from global (L2)
          if (act0) acc[0][d0] = __builtin_amdgcn_mfma_f32_16x16x32_bf16(pa0[kk], vf, acc[0][d0], 0, 0, 0);
          acc[1][d0] = __builtin_amdgcn_mfma_f32_16x16x32_bf16(pa1[kk], vf, acc[1][d0], 0, 0, 0);
        }
      }
      __builtin_amdgcn_s_setprio(0);
    }
    __syncthreads();   // K next-tile stage complete + guards K/P buffer reuse
  }

#pragma unroll
  for (int jj = 0; jj < 2; ++jj) {
    float inv[4];
#pragma unroll
    for (int j = 0; j < 4; ++j) inv[j] = 1.0f / l_run[jj][j];
#pragma unroll
    for (int d0 = 0; d0 < 8; ++d0)
#pragma unroll
      for (int j = 0; j < 4; ++j) {
        int qrow = q0 + w*32 + jj*16 + 4*g + j;
        y[(long)(b*NT + qrow)*NC + h*ND + d0*16 + r] = (bf16)(acc[jj][d0][j]*inv[j]);
      }
  }
}

extern "C" void kernel_launch(void* const* d_in, const int* in_sizes, int n_in,
                              void* d_out, int out_size, void* d_ws, size_t ws_size,
                              hipStream_t stream) {
  const float* xr     = (const float*)d_in[0];   // f32 inputs (round-6 proven)
  const void*  tok    = d_in[1];
  const float* wqkvr  = (const float*)d_in[2];
  const float* wprojr = (const float*)d_in[3];
  float* out = (float*)d_out;                    // f32 output
  char* ws = (char*)d_ws;

  bf16* qkv    = (bf16*)(ws);                       // 100,663,296 B
  bf16* yattn  = (bf16*)(ws + 100663296L);          //  33,554,432 B
  bf16* wT     = (bf16*)(ws + 134217728L);          //  25,165,824 B  W_qkv^T
  bf16* wpT    = (bf16*)(ws + 159383552L);          //   8,388,608 B  W_proj^T
  bf16* xb     = (bf16*)(ws + 167772160L);          //  33,554,432 B  bf16 x; reused as vtb
  bf16* vtb    = xb;                                //  alias: xb dead after GEMM1
  int*  maskI  = (int*)(ws + 201326592L);           //      32,768 B

  mask_prep_k<<<1, 256, 0, stream>>>(tok, maskI);
  ingest_k<<<8192, 256, 0, stream>>>(xr, xb, 16777216L);
  // fused cast+transpose of weights (f32 -> bf16, transposed)
  transpose_f32_k<<<dim3(96, 32), 256, 0, stream>>>(wqkvr, wT, NC3, NC);
  transpose_f32_k<<<dim3(32, 32), 256, 0, stream>>>(wprojr, wpT, NC, NC);
  // qkv = x @ W_qkv
  gemm_bt_k<bf16><<<dim3(48, 64), 256, 0, stream>>>(xb, wT, qkv, 8192, 6144, 2048);
  // V^T per (b,h)  (vtb aliases xb — xb dead after GEMM1)
  vtrans_k<<<dim3(32, 2, 64), 256, 0, stream>>>(qkv, vtb);
  // attention (QBLK=128, V from global)
  attn_k<<<dim3(16, 16, 4), 256, 0, stream>>>(qkv, vtb, maskI, yattn);
  // out = y @ W_proj  (f32 output)
  gemm_bt_k<float><<<dim3(16, 64), 256, 0, stream>>>(yattn, wpT, out, 8192, 2048, 2048);
}

// Round 9
// 667.799 us; speedup vs baseline: 1.8922x; 1.8922x over previous
//
#include <hip/hip_runtime.h>
#include <hip/hip_bf16.h>
#include <stdint.h>

typedef __bf16 bf16;
typedef __bf16 bf16x8 __attribute__((ext_vector_type(8)));
typedef float f32x4 __attribute__((ext_vector_type(4)));
typedef unsigned short u16;

constexpr int NB = 4;
constexpr int NT = 2048;
constexpr int NC = 2048;
constexpr int NH = 16;
constexpr int ND = 128;
constexpr int NC3 = 6144;

#define SWZP(row) ((((row) >> 2) << 1) | ((row) & 1))

__device__ __forceinline__ void gload16(const void* g, void* l) {
  __builtin_amdgcn_global_load_lds((const __attribute__((address_space(1))) void*)g,
                                   (__attribute__((address_space(3))) void*)l, 16, 0, 0);
}

// ---------------- ingest: f32 -> bf16, n multiple of 8 ----------------
__global__ __launch_bounds__(256) void ingest_k(const float* __restrict__ raw, bf16* __restrict__ out, long n) {
  long i = ((long)blockIdx.x * 256 + threadIdx.x) * 8;
  if (i >= n) return;
  f32x4 a = *(const f32x4*)(raw + i), b = *(const f32x4*)(raw + i + 4);
  bf16x8 o;
  o[0] = (bf16)a[0]; o[1] = (bf16)a[1]; o[2] = (bf16)a[2]; o[3] = (bf16)a[3];
  o[4] = (bf16)b[0]; o[5] = (bf16)b[1]; o[6] = (bf16)b[2]; o[7] = (bf16)b[3];
  *(bf16x8*)(out + i) = o;
}

// ---------------- mask format detect + expand to int32 (proven) ----------------
__global__ void mask_prep_k(const void* raw, int* out) {
  __shared__ int s_gt1, s_oddnz, s_allb, s_allf, s_allh;
  if (threadIdx.x == 0) { s_gt1 = 0; s_oddnz = 0; s_allb = 1; s_allf = 1; s_allh = 1; }
  __syncthreads();
  const unsigned int* mw = (const unsigned int*)raw;
  int gt1 = 0, oddnz = 0, allb = 1, allf = 1, allh = 1;
  for (int i = threadIdx.x; i < 2048; i += 256) {
    unsigned v = mw[i];
    if (v > 1u) gt1 = 1;
    if ((i & 1) && v) oddnz = 1;
#pragma unroll
    for (int bb = 0; bb < 4; ++bb) { unsigned by = (v >> (8*bb)) & 0xffu; if (by > 1u) allb = 0; }
    if (v != 0u && v != 0x3F800000u) allf = 0;
    unsigned lo = v & 0xffffu, hi = v >> 16;
    if ((lo != 0u && lo != 0x3F80u) || (hi != 0u && hi != 0x3F80u)) allh = 0;
  }
  if (gt1) atomicOr(&s_gt1, 1);
  if (oddnz) atomicOr(&s_oddnz, 1);
  if (!allb) atomicAnd(&s_allb, 0);
  if (!allf) atomicAnd(&s_allf, 0);
  if (!allh) atomicAnd(&s_allh, 0);
  __syncthreads();
  int mode;
  if (!s_gt1)       mode = s_oddnz ? 0 : 2;
  else if (s_allf)  mode = 3;
  else if (s_allb)  mode = 1;
  else if (s_allh)  mode = 4;
  else              mode = 0;
  for (int i = threadIdx.x; i < NB*NT; i += 256) {
    int v;
    if (mode == 0)      v = (((const int*)raw)[i] != 0);
    else if (mode == 1) v = (((const unsigned char*)raw)[i] != 0);
    else if (mode == 2) v = (((const long long*)raw)[i] != 0);
    else if (mode == 3) v = (((const unsigned int*)raw)[i] != 0);
    else                v = (((const unsigned short*)raw)[i] != 0);
    out[i] = v;
  }
}

// ---------------- fused transpose+cast: out[c][r] = bf16(in_f32[r][c]), 64x64 tiles ----------------
__global__ __launch_bounds__(256) void transpose_f32_k(const float* __restrict__ in, bf16* __restrict__ out,
                                                       int in_rs, int out_rs) {
  __shared__ __align__(16) bf16 t[64][72];
  const int r0 = blockIdx.y << 6, c0 = blockIdx.x << 6;
  const int tid = threadIdx.x;
#pragma unroll
  for (int i = 0; i < 4; ++i) {
    int slot = i*256 + tid, row = slot >> 4, c4 = slot & 15;
    f32x4 v = *(const f32x4*)(in + (long)(r0 + row)*in_rs + c0 + c4*4);
#pragma unroll
    for (int e = 0; e < 4; ++e) t[c4*4 + e][row] = (bf16)v[e];
  }
  __syncthreads();
#pragma unroll
  for (int i = 0; i < 2; ++i) {
    int slot = i*256 + tid, row = slot >> 3, c8 = slot & 7;
    bf16x8 v = *(const bf16x8*)(&t[row][c8*8]);
    *(bf16x8*)(out + (long)(c0 + row)*out_rs + r0 + c8*8) = v;
  }
}

// ---------------- V^T extraction: vt[(b*H+h)*128 + d][t] = qkv[b*T+t][4096 + h*128 + d] ----------------
__global__ __launch_bounds__(256) void vtrans_k(const bf16* __restrict__ qkv, bf16* __restrict__ vt) {
  __shared__ __align__(16) bf16 t[64][72];
  const int tt = blockIdx.x, dh = blockIdx.y, bh = blockIdx.z;
  const int b = bh >> 4, h = bh & 15;
  const int tid = threadIdx.x;
  const bf16* src = qkv + (long)(b*NT + tt*64)*NC3 + (2*NC + h*ND + dh*64);
#pragma unroll
  for (int i = 0; i < 2; ++i) {
    int slot = i*256 + tid, row = slot >> 3, c8 = slot & 7;
    bf16x8 v = *(const bf16x8*)(src + (long)row*NC3 + c8*8);
#pragma unroll
    for (int e = 0; e < 8; ++e) t[c8*8 + e][row] = v[e];
  }
  __syncthreads();
  bf16* dst = vt + ((long)bh*ND + dh*64)*NT + tt*64;
#pragma unroll
  for (int i = 0; i < 2; ++i) {
    int slot = i*256 + tid, row = slot >> 3, c8 = slot & 7;
    bf16x8 v = *(const bf16x8*)(&t[row][c8*8]);
    *(bf16x8*)(dst + (long)row*NT + c8*8) = v;
  }
}

// ---------------- GEMM: C[M,N] = A[M,K] * B, with BT = B^T [N,K] row-major ----------------
template <typename OT>
__global__ __launch_bounds__(256, 2) void gemm_bt_k(const bf16* __restrict__ A, const bf16* __restrict__ BT,
                                                    OT* __restrict__ Cout, int M, int N, int K) {
  const int tid = threadIdx.x, w = tid >> 6, l = tid & 63, g = l >> 4, r = l & 15;
  const int wr = w >> 1, wc = w & 1;
  const long m0 = (long)blockIdx.y << 7, n0 = (long)blockIdx.x << 7;
  __shared__ __align__(16) char As[16384];
  __shared__ __align__(16) char Bs[16384];

  long aoff[4], boff[4];
  char *al_[4], *bl_[4];
#pragma unroll
  for (int i = 0; i < 4; ++i) {
    int slot = i*256 + tid, row = slot >> 3, c = slot & 7, cp = c ^ (row & 7);
    aoff[i] = (m0 + row)*(long)K + cp*8;
    boff[i] = (n0 + row)*(long)K + cp*8;
    al_[i] = As + ((i*256 + w*64) << 4);
    bl_[i] = Bs + ((i*256 + w*64) << 4);
  }

  const f32x4 z4 = {0.f, 0.f, 0.f, 0.f};
  f32x4 acc[4][4];
#pragma unroll
  for (int mc = 0; mc < 4; ++mc)
#pragma unroll
    for (int nc = 0; nc < 4; ++nc) acc[mc][nc] = z4;

  for (int k0 = 0; k0 < K; k0 += 64) {
#pragma unroll
    for (int i = 0; i < 4; ++i) {
      gload16(A + aoff[i] + k0, al_[i]);
      gload16(BT + boff[i] + k0, bl_[i]);
    }
    __syncthreads();
#pragma unroll
    for (int kk = 0; kk < 2; ++kk) {
      bf16x8 af[4], bfr[4];
#pragma unroll
      for (int mc = 0; mc < 4; ++mc) {
        int row = wr*64 + mc*16 + r;
        af[mc] = *(const bf16x8*)(As + row*128 + (((kk*4 + g) ^ (row & 7)) << 4));
      }
#pragma unroll
      for (int nc = 0; nc < 4; ++nc) {
        int row = wc*64 + nc*16 + r;
        bfr[nc] = *(const bf16x8*)(Bs + row*128 + (((kk*4 + g) ^ (row & 7)) << 4));
      }
#pragma unroll
      for (int mc = 0; mc < 4; ++mc)
#pragma unroll
        for (int nc = 0; nc < 4; ++nc)
          acc[mc][nc] = __builtin_amdgcn_mfma_f32_16x16x32_bf16(af[mc], bfr[nc], acc[mc][nc], 0, 0, 0);
    }
    __syncthreads();
  }
#pragma unroll
  for (int mc = 0; mc < 4; ++mc)
#pragma unroll
    for (int nc = 0; nc < 4; ++nc)
#pragma unroll
      for (int j = 0; j < 4; ++j) {
        long mr = m0 + wr*64 + mc*16 + 4*g + j;
        long nc_ = n0 + wc*64 + nc*16 + r;
        Cout[mr*(long)N + nc_] = (OT)acc[mc][nc][j];
      }
}

// ---------------- fused causal+masked flash attention, 512 threads (8 waves x 16 q-rows) ----------------
// block = (qx,h,b): QBLK=128 q-rows. KVBLK=64. K,V double-buffered in LDS (82KB total).
// 8 waves -> 2 waves/SIMD within one block: softmax of one wave overlaps MFMA of its SIMD partner.
__global__ __launch_bounds__(512, 1) void attn_k(const bf16* __restrict__ qkv, const bf16* __restrict__ vt,
                                                 const int* __restrict__ mask, bf16* __restrict__ y) {
  const int qx = blockIdx.x, h = blockIdx.y, b = blockIdx.z;
  const int qb = (qx & 1) ? (15 - (qx >> 1)) : (qx >> 1);   // work-balance remap (bijective)
  const int tid = threadIdx.x, w = tid >> 6, l = tid & 63, g = l >> 4, r = l & 15;
  const int q0 = qb << 7;
  const int bh = b*NH + h;
  const int ntiles = (q0 + 128) >> 6;                        // 2qb+2

  __shared__ __align__(16) char Klds[2][16384];   // [64 key][128 d], swizzled 16B slots
  __shared__ __align__(16) char Vlds[2][16384];   // [128 d][64 key], swizzled
  __shared__ __align__(16) char Plds[16384];      // per-wave [16 q][64 key] bf16, SWZP
  __shared__ char Mc[2048];                       // key mask (char) for this b
  char* Pl = Plds + (w << 11);

  for (int i = tid; i < q0 + 128; i += 512) Mc[i] = (char)(mask[b*NT + i] != 0);

  // staging: K tile 64 rows x 16 slots = 1024 slots; V^T tile 128 rows x 8 slots = 1024 slots.
  // 512 threads -> 2 gload16 each per tile per tensor. LDS dest is wave-linear (slot<<4).
  long koff[2], voff[2];
  int slo[2];
#pragma unroll
  for (int i = 0; i < 2; ++i) {
    int slot = i*512 + tid;
    int krow = slot >> 4, kc = slot & 15, kcp = kc ^ (krow & 7);
    koff[i] = (long)krow*NC3 + kcp*8;
    int vrow = slot >> 3, vc = slot & 7, vcp = vc ^ (vrow & 7);
    voff[i] = (long)vrow*NT + vcp*8;
    slo[i] = (i*512 + w*64) << 4;
  }
  const bf16* kbase0 = qkv + (long)(b*NT)*NC3 + (NC + h*ND);
  const bf16* vbase0 = vt + (long)bh*ND*NT;

  bf16x8 qf[4];
  {
    const int qrow = q0 + w*16 + r;
    const bf16* qp = qkv + (long)(b*NT + qrow)*NC3 + h*ND + g*8;
#pragma unroll
    for (int dk = 0; dk < 4; ++dk) qf[dk] = *(const bf16x8*)(qp + dk*32);
  }

  const f32x4 z4 = {0.f, 0.f, 0.f, 0.f};
  f32x4 acc[8];
#pragma unroll
  for (int i = 0; i < 8; ++i) acc[i] = z4;
  float m_run[4], l_run[4];
#pragma unroll
  for (int j = 0; j < 4; ++j) { m_run[j] = -3.0e38f; l_run[j] = 0.f; }

  const float SCL = 0.08838834764831845f * 1.4426950408889634f;  // 1/sqrt(128) * log2(e)

  // prologue: stage tile 0 into buffer 0
#pragma unroll
  for (int i = 0; i < 2; ++i) {
    gload16(kbase0 + koff[i], Klds[0] + slo[i]);
    gload16(vbase0 + voff[i], Vlds[0] + slo[i]);
  }
  __syncthreads();

  for (int kt = 0; kt < ntiles; ++kt) {
    const int cur = kt & 1;
    if (kt + 1 < ntiles) {
      const bf16* kb = kbase0 + (long)((kt+1)*64)*NC3;
      const bf16* vb = vbase0 + (kt+1)*64;
#pragma unroll
      for (int i = 0; i < 2; ++i) {
        gload16(kb + koff[i], Klds[cur^1] + slo[i]);
        gload16(vb + voff[i], Vlds[cur^1] + slo[i]);
      }
    }
    const char* Kl = Klds[cur];
    const char* Vl = Vlds[cur];
    const int key0 = kt*64;
    const bool act = (key0 <= q0 + w*16 + 15);     // wave-uniform causal skip

    if (act) {
      char mvc[4];
#pragma unroll
      for (int kc = 0; kc < 4; ++kc) mvc[kc] = Mc[key0 + kc*16 + r];
      const int qr_lane = q0 + w*16 + 4*g;         // +j gives this lane's q-rows

      float tv[4][4];
      float tmax[4] = {-3.0e38f, -3.0e38f, -3.0e38f, -3.0e38f};
      __builtin_amdgcn_s_setprio(1);
#pragma unroll
      for (int kc = 0; kc < 4; ++kc) {
        const int krow = kc*16 + r;
        f32x4 s = z4;
#pragma unroll
        for (int dk = 0; dk < 4; ++dk) {
          bf16x8 kf = *(const bf16x8*)(Kl + krow*256 + (((dk*4 + g) ^ (krow & 7)) << 4));
          s = __builtin_amdgcn_mfma_f32_16x16x32_bf16(qf[dk], kf, s, 0, 0, 0);
        }
        const int key = key0 + krow;
#pragma unroll
        for (int j = 0; j < 4; ++j) {
          float sv = (mvc[kc] && key <= qr_lane + j) ? s[j]*SCL : -3.0e38f;
          tv[kc][j] = sv;
          tmax[j] = fmaxf(tmax[j], sv);
        }
      }
      __builtin_amdgcn_s_setprio(0);
#pragma unroll
      for (int j = 0; j < 4; ++j) {
#pragma unroll
        for (int off = 1; off < 16; off <<= 1) tmax[j] = fmaxf(tmax[j], __shfl_xor(tmax[j], off));
      }
      float al[4], rs[4];
#pragma unroll
      for (int j = 0; j < 4; ++j) {
        float mn = fmaxf(m_run[j], tmax[j]);
        al[j] = exp2f(m_run[j] - mn);
        m_run[j] = mn;
        rs[j] = 0.f;
      }
#pragma unroll
      for (int kc = 0; kc < 4; ++kc) {
#pragma unroll
        for (int j = 0; j < 4; ++j) {
          float p = exp2f(tv[kc][j] - m_run[j]);
          rs[j] += p;
          int prow = 4*g + j;
          int cb = (kc*16 + r)*2;
          int sl = (cb >> 4) ^ SWZP(prow);
          *(u16*)(Pl + prow*128 + (sl << 4) + (cb & 15)) = __builtin_bit_cast(u16, (bf16)p);
        }
      }
#pragma unroll
      for (int j = 0; j < 4; ++j) {
#pragma unroll
        for (int off = 1; off < 16; off <<= 1) rs[j] += __shfl_xor(rs[j], off);
        l_run[j] = l_run[j]*al[j] + rs[j];
      }
#pragma unroll
      for (int d0 = 0; d0 < 8; ++d0)
#pragma unroll
        for (int j = 0; j < 4; ++j) acc[d0][j] *= al[j];
      // P write -> read fence (same-wave DS; pin hw counter + scheduler, rule #18)
      asm volatile("s_waitcnt lgkmcnt(0)" ::: "memory");
      __builtin_amdgcn_sched_barrier(0);
      bf16x8 pa[2];
#pragma unroll
      for (int kk = 0; kk < 2; ++kk)
        pa[kk] = *(const bf16x8*)(Pl + r*128 + (((kk*4 + g) ^ SWZP(r)) << 4));
      __builtin_amdgcn_s_setprio(1);
#pragma unroll
      for (int d0 = 0; d0 < 8; ++d0) {
        const int vrow = d0*16 + r;
#pragma unroll
        for (int kk = 0; kk < 2; ++kk) {
          bf16x8 vf = *(const bf16x8*)(Vl + vrow*128 + (((kk*4 + g) ^ (vrow & 7)) << 4));
          acc[d0] = __builtin_amdgcn_mfma_f32_16x16x32_bf16(pa[kk], vf, acc[d0], 0, 0, 0);
        }
      }
      __builtin_amdgcn_s_setprio(0);
    }
    __syncthreads();   // next-tile stage complete + guards K/V/P buffer reuse
  }

  float inv[4];
#pragma unroll
  for (int j = 0; j < 4; ++j) inv[j] = 1.0f / l_run[j];
#pragma unroll
  for (int d0 = 0; d0 < 8; ++d0)
#pragma unroll
    for (int j = 0; j < 4; ++j) {
      int qrow = q0 + w*16 + 4*g + j;
      y[(long)(b*NT + qrow)*NC + h*ND + d0*16 + r] = (bf16)(acc[d0][j]*inv[j]);
    }
}

extern "C" void kernel_launch(void* const* d_in, const int* in_sizes, int n_in,
                              void* d_out, int out_size, void* d_ws, size_t ws_size,
                              hipStream_t stream) {
  const float* xr     = (const float*)d_in[0];   // f32 inputs (round-6 proven)
  const void*  tok    = d_in[1];
  const float* wqkvr  = (const float*)d_in[2];
  const float* wprojr = (const float*)d_in[3];
  float* out = (float*)d_out;                    // f32 output
  char* ws = (char*)d_ws;

  bf16* qkv    = (bf16*)(ws);                       // 100,663,296 B
  bf16* yattn  = (bf16*)(ws + 100663296L);          //  33,554,432 B
  bf16* wT     = (bf16*)(ws + 134217728L);          //  25,165,824 B  W_qkv^T
  bf16* wpT    = (bf16*)(ws + 159383552L);          //   8,388,608 B  W_proj^T
  bf16* xb     = (bf16*)(ws + 167772160L);          //  33,554,432 B  bf16 x; reused as vtb
  bf16* vtb    = xb;                                //  alias: xb dead after GEMM1
  int*  maskI  = (int*)(ws + 201326592L);           //      32,768 B

  mask_prep_k<<<1, 256, 0, stream>>>(tok, maskI);
  ingest_k<<<8192, 256, 0, stream>>>(xr, xb, 16777216L);
  // fused cast+transpose of weights (f32 -> bf16, transposed)
  transpose_f32_k<<<dim3(96, 32), 256, 0, stream>>>(wqkvr, wT, NC3, NC);
  transpose_f32_k<<<dim3(32, 32), 256, 0, stream>>>(wprojr, wpT, NC, NC);
  // qkv = x @ W_qkv
  gemm_bt_k<bf16><<<dim3(48, 64), 256, 0, stream>>>(xb, wT, qkv, 8192, 6144, 2048);
  // V^T per (b,h)  (vtb aliases xb — xb dead after GEMM1)
  vtrans_k<<<dim3(32, 2, 64), 256, 0, stream>>>(qkv, vtb);
  // attention (512 threads, 8 waves, QBLK=128, K/V in LDS)
  attn_k<<<dim3(16, 16, 4), 512, 0, stream>>>(qkv, vtb, maskI, yattn);
  // out = y @ W_proj  (f32 output)
  gemm_bt_k<float><<<dim3(16, 64), 256, 0, stream>>>(yattn, wpT, out, 8192, 2048, 2048);
}

// Round 10
// 603.537 us; speedup vs baseline: 2.0937x; 1.1065x over previous
//
#include <hip/hip_runtime.h>
#include <hip/hip_bf16.h>
#include <stdint.h>

typedef __bf16 bf16;
typedef __bf16 bf16x8 __attribute__((ext_vector_type(8)));
typedef float f32x4 __attribute__((ext_vector_type(4)));
typedef unsigned short u16;
typedef unsigned int u32;

constexpr int NB = 4;
constexpr int NT = 2048;
constexpr int NC = 2048;
constexpr int NH = 16;
constexpr int ND = 128;
constexpr int NC3 = 6144;

__device__ __forceinline__ void gload16(const void* g, void* l) {
  __builtin_amdgcn_global_load_lds((const __attribute__((address_space(1))) void*)g,
                                   (__attribute__((address_space(3))) void*)l, 16, 0, 0);
}

__device__ __forceinline__ u32 pack_bf16(float a, float b) {
  return (u32)__builtin_bit_cast(u16, (bf16)a) | ((u32)__builtin_bit_cast(u16, (bf16)b) << 16);
}

// ---------------- ingest: f32 -> bf16 ----------------
__global__ __launch_bounds__(256) void ingest_k(const float* __restrict__ raw, bf16* __restrict__ out, long n) {
  long i = ((long)blockIdx.x * 256 + threadIdx.x) * 8;
  if (i >= n) return;
  f32x4 a = *(const f32x4*)(raw + i), b = *(const f32x4*)(raw + i + 4);
  bf16x8 o;
  o[0] = (bf16)a[0]; o[1] = (bf16)a[1]; o[2] = (bf16)a[2]; o[3] = (bf16)a[3];
  o[4] = (bf16)b[0]; o[5] = (bf16)b[1]; o[6] = (bf16)b[2]; o[7] = (bf16)b[3];
  *(bf16x8*)(out + i) = o;
}

// ---------------- mask format detect + expand to int32 (proven) ----------------
__global__ void mask_prep_k(const void* raw, int* out) {
  __shared__ int s_gt1, s_oddnz, s_allb, s_allf, s_allh;
  if (threadIdx.x == 0) { s_gt1 = 0; s_oddnz = 0; s_allb = 1; s_allf = 1; s_allh = 1; }
  __syncthreads();
  const unsigned int* mw = (const unsigned int*)raw;
  int gt1 = 0, oddnz = 0, allb = 1, allf = 1, allh = 1;
  for (int i = threadIdx.x; i < 2048; i += 256) {
    unsigned v = mw[i];
    if (v > 1u) gt1 = 1;
    if ((i & 1) && v) oddnz = 1;
#pragma unroll
    for (int bb = 0; bb < 4; ++bb) { unsigned by = (v >> (8*bb)) & 0xffu; if (by > 1u) allb = 0; }
    if (v != 0u && v != 0x3F800000u) allf = 0;
    unsigned lo = v & 0xffffu, hi = v >> 16;
    if ((lo != 0u && lo != 0x3F80u) || (hi != 0u && hi != 0x3F80u)) allh = 0;
  }
  if (gt1) atomicOr(&s_gt1, 1);
  if (oddnz) atomicOr(&s_oddnz, 1);
  if (!allb) atomicAnd(&s_allb, 0);
  if (!allf) atomicAnd(&s_allf, 0);
  if (!allh) atomicAnd(&s_allh, 0);
  __syncthreads();
  int mode;
  if (!s_gt1)       mode = s_oddnz ? 0 : 2;
  else if (s_allf)  mode = 3;
  else if (s_allb)  mode = 1;
  else if (s_allh)  mode = 4;
  else              mode = 0;
  for (int i = threadIdx.x; i < NB*NT; i += 256) {
    int v;
    if (mode == 0)      v = (((const int*)raw)[i] != 0);
    else if (mode == 1) v = (((const unsigned char*)raw)[i] != 0);
    else if (mode == 2) v = (((const long long*)raw)[i] != 0);
    else if (mode == 3) v = (((const unsigned int*)raw)[i] != 0);
    else                v = (((const unsigned short*)raw)[i] != 0);
    out[i] = v;
  }
}

// ---------------- fused transpose+cast: out[c][r] = bf16(in_f32[r][c]) ----------------
__global__ __launch_bounds__(256) void transpose_f32_k(const float* __restrict__ in, bf16* __restrict__ out,
                                                       int in_rs, int out_rs) {
  __shared__ __align__(16) bf16 t[64][72];
  const int r0 = blockIdx.y << 6, c0 = blockIdx.x << 6;
  const int tid = threadIdx.x;
#pragma unroll
  for (int i = 0; i < 4; ++i) {
    int slot = i*256 + tid, row = slot >> 4, c4 = slot & 15;
    f32x4 v = *(const f32x4*)(in + (long)(r0 + row)*in_rs + c0 + c4*4);
#pragma unroll
    for (int e = 0; e < 4; ++e) t[c4*4 + e][row] = (bf16)v[e];
  }
  __syncthreads();
#pragma unroll
  for (int i = 0; i < 2; ++i) {
    int slot = i*256 + tid, row = slot >> 3, c8 = slot & 7;
    bf16x8 v = *(const bf16x8*)(&t[row][c8*8]);
    *(bf16x8*)(out + (long)(c0 + row)*out_rs + r0 + c8*8) = v;
  }
}

// ---------------- V^T extraction ----------------
__global__ __launch_bounds__(256) void vtrans_k(const bf16* __restrict__ qkv, bf16* __restrict__ vt) {
  __shared__ __align__(16) bf16 t[64][72];
  const int tt = blockIdx.x, dh = blockIdx.y, bh = blockIdx.z;
  const int b = bh >> 4, h = bh & 15;
  const int tid = threadIdx.x;
  const bf16* src = qkv + (long)(b*NT + tt*64)*NC3 + (2*NC + h*ND + dh*64);
#pragma unroll
  for (int i = 0; i < 2; ++i) {
    int slot = i*256 + tid, row = slot >> 3, c8 = slot & 7;
    bf16x8 v = *(const bf16x8*)(src + (long)row*NC3 + c8*8);
#pragma unroll
    for (int e = 0; e < 8; ++e) t[c8*8 + e][row] = v[e];
  }
  __syncthreads();
  bf16* dst = vt + ((long)bh*ND + dh*64)*NT + tt*64;
#pragma unroll
  for (int i = 0; i < 2; ++i) {
    int slot = i*256 + tid, row = slot >> 3, c8 = slot & 7;
    bf16x8 v = *(const bf16x8*)(&t[row][c8*8]);
    *(bf16x8*)(dst + (long)row*NT + c8*8) = v;
  }
}

// ---------------- GEMM: C[M,N] = A[M,K] * B, with BT = B^T [N,K] row-major ----------------
template <typename OT>
__global__ __launch_bounds__(256, 2) void gemm_bt_k(const bf16* __restrict__ A, const bf16* __restrict__ BT,
                                                    OT* __restrict__ Cout, int M, int N, int K) {
  const int tid = threadIdx.x, w = tid >> 6, l = tid & 63, g = l >> 4, r = l & 15;
  const int wr = w >> 1, wc = w & 1;
  const long m0 = (long)blockIdx.y << 7, n0 = (long)blockIdx.x << 7;
  __shared__ __align__(16) char As[16384];
  __shared__ __align__(16) char Bs[16384];

  long aoff[4], boff[4];
  char *al_[4], *bl_[4];
#pragma unroll
  for (int i = 0; i < 4; ++i) {
    int slot = i*256 + tid, row = slot >> 3, c = slot & 7, cp = c ^ (row & 7);
    aoff[i] = (m0 + row)*(long)K + cp*8;
    boff[i] = (n0 + row)*(long)K + cp*8;
    al_[i] = As + ((i*256 + w*64) << 4);
    bl_[i] = Bs + ((i*256 + w*64) << 4);
  }

  const f32x4 z4 = {0.f, 0.f, 0.f, 0.f};
  f32x4 acc[4][4];
#pragma unroll
  for (int mc = 0; mc < 4; ++mc)
#pragma unroll
    for (int nc = 0; nc < 4; ++nc) acc[mc][nc] = z4;

  for (int k0 = 0; k0 < K; k0 += 64) {
#pragma unroll
    for (int i = 0; i < 4; ++i) {
      gload16(A + aoff[i] + k0, al_[i]);
      gload16(BT + boff[i] + k0, bl_[i]);
    }
    __syncthreads();
#pragma unroll
    for (int kk = 0; kk < 2; ++kk) {
      bf16x8 af[4], bfr[4];
#pragma unroll
      for (int mc = 0; mc < 4; ++mc) {
        int row = wr*64 + mc*16 + r;
        af[mc] = *(const bf16x8*)(As + row*128 + (((kk*4 + g) ^ (row & 7)) << 4));
      }
#pragma unroll
      for (int nc = 0; nc < 4; ++nc) {
        int row = wc*64 + nc*16 + r;
        bfr[nc] = *(const bf16x8*)(Bs + row*128 + (((kk*4 + g) ^ (row & 7)) << 4));
      }
#pragma unroll
      for (int mc = 0; mc < 4; ++mc)
#pragma unroll
        for (int nc = 0; nc < 4; ++nc)
          acc[mc][nc] = __builtin_amdgcn_mfma_f32_16x16x32_bf16(af[mc], bfr[nc], acc[mc][nc], 0, 0, 0);
    }
    __syncthreads();
  }
#pragma unroll
  for (int mc = 0; mc < 4; ++mc)
#pragma unroll
    for (int nc = 0; nc < 4; ++nc)
#pragma unroll
      for (int j = 0; j < 4; ++j) {
        long mr = m0 + wr*64 + mc*16 + 4*g + j;
        long nc_ = n0 + wc*64 + nc*16 + r;
        Cout[mr*(long)N + nc_] = (OT)acc[mc][nc][j];
      }
}

// ---------------- flash attention v10: swapped-QK in-register softmax ----------------
// block = (qx,h,b): 64 q-rows, 4 waves x 16 rows (lane's own q-row = r). K,V dbuf in LDS.
// mfma(K,Q): lane (r,g) holds S[q=r][key=kc*16+4g+j] -> softmax nearly all in-register.
__global__ __launch_bounds__(256, 2) void attn_k(const bf16* __restrict__ qkv, const bf16* __restrict__ vt,
                                                 const int* __restrict__ mask, bf16* __restrict__ y) {
  const int qx = blockIdx.x, h = blockIdx.y, b = blockIdx.z;
  const int qt = (qx & 1) ? (31 - (qx >> 1)) : (qx >> 1);   // work-balance remap (bijective)
  const int tid = threadIdx.x, w = tid >> 6, l = tid & 63, g = l >> 4, r = l & 15;
  const int q0 = qt << 6;
  const int bh = b*NH + h;
  const int ntiles = qt + 1;
  const int qrow = q0 + w*16 + r;                 // this lane's q-row

  __shared__ __align__(16) char Klds[2][16384];   // [64 key][128 d], swizzled 16B slots
  __shared__ __align__(16) char Vlds[2][16384];   // [128 d][64 key], swizzled
  __shared__ __align__(16) char Plds[8192];       // per-wave [16 q][64 key] bf16, xor (r&7)<<4
  __shared__ char Mc[2048];                       // key mask (char) for this b
  char* Pl = Plds + (w << 11);

  for (int i = tid; i < q0 + 64; i += 256) Mc[i] = (char)(mask[b*NT + i] != 0);

  long koff[4], voff[4];
  int klo[4];
#pragma unroll
  for (int i = 0; i < 4; ++i) {
    int slot = i*256 + tid;                       // K: 64 rows x 16 slots
    int row = slot >> 4, c = slot & 15, cp = c ^ (row & 7);
    koff[i] = (long)row*NC3 + cp*8;
    klo[i] = (i*256 + w*64) << 4;
    int vrow = slot >> 3, vc = slot & 7, vcp = vc ^ (vrow & 7);   // VT: 128 rows x 8 slots
    voff[i] = (long)vrow*NT + vcp*8;
  }
  const bf16* kbase0 = qkv + (long)(b*NT)*NC3 + (NC + h*ND);
  const bf16* vbase0 = vt + (long)bh*ND*NT;

  bf16x8 qf[4];
  {
    const bf16* qp = qkv + (long)(b*NT + qrow)*NC3 + h*ND + g*8;
#pragma unroll
    for (int dk = 0; dk < 4; ++dk) qf[dk] = *(const bf16x8*)(qp + dk*32);
  }

  const f32x4 z4 = {0.f, 0.f, 0.f, 0.f};
  f32x4 acc[8];
#pragma unroll
  for (int i = 0; i < 8; ++i) acc[i] = z4;
  float m_run = 0.0f;   // init 0 (not -inf): fully-masked tiles then give p=exp2(-3e38-m)=0 under defer-max
  float l_run = 0.0f;

  const float SCL = 0.08838834764831845f * 1.4426950408889634f;  // 1/sqrt(128) * log2(e)

  // prologue: stage tile 0 into buffer 0
#pragma unroll
  for (int i = 0; i < 4; ++i) {
    gload16(kbase0 + koff[i], Klds[0] + klo[i]);
    gload16(vbase0 + voff[i], Vlds[0] + klo[i]);
  }
  __syncthreads();

  for (int kt = 0; kt < ntiles; ++kt) {
    const int cur = kt & 1;
    if (kt + 1 < ntiles) {
      const bf16* kb = kbase0 + (long)((kt+1)*64)*NC3;
      const bf16* vb = vbase0 + (kt+1)*64;
#pragma unroll
      for (int i = 0; i < 4; ++i) {
        gload16(kb + koff[i], Klds[cur^1] + klo[i]);
        gload16(vb + voff[i], Vlds[cur^1] + klo[i]);
      }
    }
    const char* Kl = Klds[cur];
    const char* Vl = Vlds[cur];
    const int key0 = kt*64;
    const bool act = (key0 <= q0 + w*16 + 15);     // wave-uniform causal skip

    if (act) {
      u32 mw_[4];
#pragma unroll
      for (int kc = 0; kc < 4; ++kc) mw_[kc] = *(const u32*)(Mc + key0 + kc*16 + 4*g);

      float tv[4][4];
      __builtin_amdgcn_s_setprio(1);
#pragma unroll
      for (int kc = 0; kc < 4; ++kc) {
        const int krow = kc*16 + r;
        f32x4 s = z4;
#pragma unroll
        for (int dk = 0; dk < 4; ++dk) {
          bf16x8 kf = *(const bf16x8*)(Kl + krow*256 + (((dk*4 + g) ^ (krow & 7)) << 4));
          s = __builtin_amdgcn_mfma_f32_16x16x32_bf16(kf, qf[dk], s, 0, 0, 0);  // SWAPPED
        }
#pragma unroll
        for (int j = 0; j < 4; ++j) {
          const int key = key0 + kc*16 + 4*g + j;
          const bool ok = ((mw_[kc] >> (8*j)) & 0xffu) && (key <= qrow);
          tv[kc][j] = ok ? s[j]*SCL : -3.0e38f;
        }
      }
      __builtin_amdgcn_s_setprio(0);

      // row max: in-lane 16 + 2 shfl across g
      float tmax = -3.0e38f;
#pragma unroll
      for (int kc = 0; kc < 4; ++kc)
#pragma unroll
        for (int j = 0; j < 4; ++j) tmax = fmaxf(tmax, tv[kc][j]);
      tmax = fmaxf(tmax, __shfl_xor(tmax, 16));
      tmax = fmaxf(tmax, __shfl_xor(tmax, 32));

      // defer-max (T13, THR=8 in log2 domain)
      if (!__all(tmax <= m_run + 8.0f)) {
        float mn = fmaxf(m_run, tmax);
        float al = exp2f(m_run - mn);
        m_run = mn;
        l_run *= al;
        float alj[4];
#pragma unroll
        for (int j = 0; j < 4; ++j) alj[j] = __shfl(al, 4*g + j);
#pragma unroll
        for (int d0 = 0; d0 < 8; ++d0)
#pragma unroll
          for (int j = 0; j < 4; ++j) acc[d0][j] *= alj[j];
      }

      // p = exp2(tv - m), in-lane sum, pack to bf16 pairs, write P (4x ds_write_b64)
      float rs = 0.f;
      u32 pk0[4], pk1[4];
#pragma unroll
      for (int kc = 0; kc < 4; ++kc) {
        float p0 = exp2f(tv[kc][0] - m_run), p1 = exp2f(tv[kc][1] - m_run);
        float p2 = exp2f(tv[kc][2] - m_run), p3 = exp2f(tv[kc][3] - m_run);
        rs += (p0 + p1) + (p2 + p3);
        pk0[kc] = pack_bf16(p0, p1);
        pk1[kc] = pack_bf16(p2, p3);
      }
      rs += __shfl_xor(rs, 16);
      rs += __shfl_xor(rs, 32);
      l_run += rs;
#pragma unroll
      for (int kc = 0; kc < 4; ++kc) {
        const int off = (kc*32 + g*8) ^ ((r & 7) << 4);
        uint2 wv; wv.x = pk0[kc]; wv.y = pk1[kc];
        *(uint2*)(Pl + r*128 + off) = wv;
      }
      // P write -> read fence (same-wave DS; pin hw counter + scheduler, rule #18)
      asm volatile("s_waitcnt lgkmcnt(0)" ::: "memory");
      __builtin_amdgcn_sched_barrier(0);
      bf16x8 pa[2];
#pragma unroll
      for (int kk = 0; kk < 2; ++kk)
        pa[kk] = *(const bf16x8*)(Pl + r*128 + ((kk*64 + g*16) ^ ((r & 7) << 4)));

      __builtin_amdgcn_s_setprio(1);
#pragma unroll
      for (int d0 = 0; d0 < 8; ++d0) {
        const int vrow = d0*16 + r;
#pragma unroll
        for (int kk = 0; kk < 2; ++kk) {
          bf16x8 vf = *(const bf16x8*)(Vl + vrow*128 + (((kk*4 + g) ^ (vrow & 7)) << 4));
          acc[d0] = __builtin_amdgcn_mfma_f32_16x16x32_bf16(pa[kk], vf, acc[d0], 0, 0, 0);
        }
      }
      __builtin_amdgcn_s_setprio(0);
    }
    __syncthreads();   // next-tile stage complete + guards K/V/P buffer reuse
  }

  // epilogue: normalize; acc rows are q=4g+j, l_run lives at lanes r'=4g+j (uniform over their g)
  float lr[4];
#pragma unroll
  for (int j = 0; j < 4; ++j) lr[j] = __shfl(l_run, 4*g + j);
#pragma unroll
  for (int d0 = 0; d0 < 8; ++d0)
#pragma unroll
    for (int j = 0; j < 4; ++j) {
      int qr = q0 + w*16 + 4*g + j;
      y[(long)(b*NT + qr)*NC + h*ND + d0*16 + r] = (bf16)(acc[d0][j] / lr[j]);
    }
}

extern "C" void kernel_launch(void* const* d_in, const int* in_sizes, int n_in,
                              void* d_out, int out_size, void* d_ws, size_t ws_size,
                              hipStream_t stream) {
  const float* xr     = (const float*)d_in[0];   // f32 inputs (round-6 proven)
  const void*  tok    = d_in[1];
  const float* wqkvr  = (const float*)d_in[2];
  const float* wprojr = (const float*)d_in[3];
  float* out = (float*)d_out;                    // f32 output
  char* ws = (char*)d_ws;

  bf16* qkv    = (bf16*)(ws);                       // 100,663,296 B
  bf16* yattn  = (bf16*)(ws + 100663296L);          //  33,554,432 B
  bf16* wT     = (bf16*)(ws + 134217728L);          //  25,165,824 B  W_qkv^T
  bf16* wpT    = (bf16*)(ws + 159383552L);          //   8,388,608 B  W_proj^T
  bf16* xb     = (bf16*)(ws + 167772160L);          //  33,554,432 B  bf16 x; reused as vtb
  bf16* vtb    = xb;                                //  alias: xb dead after GEMM1
  int*  maskI  = (int*)(ws + 201326592L);           //      32,768 B

  mask_prep_k<<<1, 256, 0, stream>>>(tok, maskI);
  ingest_k<<<8192, 256, 0, stream>>>(xr, xb, 16777216L);
  // fused cast+transpose of weights (f32 -> bf16, transposed)
  transpose_f32_k<<<dim3(96, 32), 256, 0, stream>>>(wqkvr, wT, NC3, NC);
  transpose_f32_k<<<dim3(32, 32), 256, 0, stream>>>(wprojr, wpT, NC, NC);
  // qkv = x @ W_qkv
  gemm_bt_k<bf16><<<dim3(48, 64), 256, 0, stream>>>(xb, wT, qkv, 8192, 6144, 2048);
  // V^T per (b,h)  (vtb aliases xb — xb dead after GEMM1)
  vtrans_k<<<dim3(32, 2, 64), 256, 0, stream>>>(qkv, vtb);
  // attention (swapped-QK in-register softmax)
  attn_k<<<dim3(32, 16, 4), 256, 0, stream>>>(qkv, vtb, maskI, yattn);
  // out = y @ W_proj  (f32 output)
  gemm_bt_k<float><<<dim3(16, 64), 256, 0, stream>>>(yattn, wpT, out, 8192, 2048, 2048);
}

// Round 11
// 589.799 us; speedup vs baseline: 2.1425x; 1.0233x over previous
//
#include <hip/hip_runtime.h>
#include <hip/hip_bf16.h>
#include <stdint.h>

typedef __bf16 bf16;
typedef __bf16 bf16x8 __attribute__((ext_vector_type(8)));
typedef float f32x4 __attribute__((ext_vector_type(4)));
typedef unsigned short u16;
typedef unsigned int u32;

constexpr int NB = 4;
constexpr int NT = 2048;
constexpr int NC = 2048;
constexpr int NH = 16;
constexpr int ND = 128;
constexpr int NC3 = 6144;

__device__ __forceinline__ void gload16(const void* g, void* l) {
  __builtin_amdgcn_global_load_lds((const __attribute__((address_space(1))) void*)g,
                                   (__attribute__((address_space(3))) void*)l, 16, 0, 0);
}

__device__ __forceinline__ u32 pack_bf16(float a, float b) {
  return (u32)__builtin_bit_cast(u16, (bf16)a) | ((u32)__builtin_bit_cast(u16, (bf16)b) << 16);
}

// ---------------- ingest: f32 -> bf16 ----------------
__global__ __launch_bounds__(256) void ingest_k(const float* __restrict__ raw, bf16* __restrict__ out, long n) {
  long i = ((long)blockIdx.x * 256 + threadIdx.x) * 8;
  if (i >= n) return;
  f32x4 a = *(const f32x4*)(raw + i), b = *(const f32x4*)(raw + i + 4);
  bf16x8 o;
  o[0] = (bf16)a[0]; o[1] = (bf16)a[1]; o[2] = (bf16)a[2]; o[3] = (bf16)a[3];
  o[4] = (bf16)b[0]; o[5] = (bf16)b[1]; o[6] = (bf16)b[2]; o[7] = (bf16)b[3];
  *(bf16x8*)(out + i) = o;
}

// ---------------- mask format detect + expand to int32 (proven) ----------------
__global__ void mask_prep_k(const void* raw, int* out) {
  __shared__ int s_gt1, s_oddnz, s_allb, s_allf, s_allh;
  if (threadIdx.x == 0) { s_gt1 = 0; s_oddnz = 0; s_allb = 1; s_allf = 1; s_allh = 1; }
  __syncthreads();
  const unsigned int* mw = (const unsigned int*)raw;
  int gt1 = 0, oddnz = 0, allb = 1, allf = 1, allh = 1;
  for (int i = threadIdx.x; i < 2048; i += 256) {
    unsigned v = mw[i];
    if (v > 1u) gt1 = 1;
    if ((i & 1) && v) oddnz = 1;
#pragma unroll
    for (int bb = 0; bb < 4; ++bb) { unsigned by = (v >> (8*bb)) & 0xffu; if (by > 1u) allb = 0; }
    if (v != 0u && v != 0x3F800000u) allf = 0;
    unsigned lo = v & 0xffffu, hi = v >> 16;
    if ((lo != 0u && lo != 0x3F80u) || (hi != 0u && hi != 0x3F80u)) allh = 0;
  }
  if (gt1) atomicOr(&s_gt1, 1);
  if (oddnz) atomicOr(&s_oddnz, 1);
  if (!allb) atomicAnd(&s_allb, 0);
  if (!allf) atomicAnd(&s_allf, 0);
  if (!allh) atomicAnd(&s_allh, 0);
  __syncthreads();
  int mode;
  if (!s_gt1)       mode = s_oddnz ? 0 : 2;
  else if (s_allf)  mode = 3;
  else if (s_allb)  mode = 1;
  else if (s_allh)  mode = 4;
  else              mode = 0;
  for (int i = threadIdx.x; i < NB*NT; i += 256) {
    int v;
    if (mode == 0)      v = (((const int*)raw)[i] != 0);
    else if (mode == 1) v = (((const unsigned char*)raw)[i] != 0);
    else if (mode == 2) v = (((const long long*)raw)[i] != 0);
    else if (mode == 3) v = (((const unsigned int*)raw)[i] != 0);
    else                v = (((const unsigned short*)raw)[i] != 0);
    out[i] = v;
  }
}

// ---------------- fused transpose+cast: out[c][r] = bf16(in_f32[r][c]) ----------------
__global__ __launch_bounds__(256) void transpose_f32_k(const float* __restrict__ in, bf16* __restrict__ out,
                                                       int in_rs, int out_rs) {
  __shared__ __align__(16) bf16 t[64][72];
  const int r0 = blockIdx.y << 6, c0 = blockIdx.x << 6;
  const int tid = threadIdx.x;
#pragma unroll
  for (int i = 0; i < 4; ++i) {
    int slot = i*256 + tid, row = slot >> 4, c4 = slot & 15;
    f32x4 v = *(const f32x4*)(in + (long)(r0 + row)*in_rs + c0 + c4*4);
#pragma unroll
    for (int e = 0; e < 4; ++e) t[c4*4 + e][row] = (bf16)v[e];
  }
  __syncthreads();
#pragma unroll
  for (int i = 0; i < 2; ++i) {
    int slot = i*256 + tid, row = slot >> 3, c8 = slot & 7;
    bf16x8 v = *(const bf16x8*)(&t[row][c8*8]);
    *(bf16x8*)(out + (long)(c0 + row)*out_rs + r0 + c8*8) = v;
  }
}

// ---------------- V^T extraction ----------------
__global__ __launch_bounds__(256) void vtrans_k(const bf16* __restrict__ qkv, bf16* __restrict__ vt) {
  __shared__ __align__(16) bf16 t[64][72];
  const int tt = blockIdx.x, dh = blockIdx.y, bh = blockIdx.z;
  const int b = bh >> 4, h = bh & 15;
  const int tid = threadIdx.x;
  const bf16* src = qkv + (long)(b*NT + tt*64)*NC3 + (2*NC + h*ND + dh*64);
#pragma unroll
  for (int i = 0; i < 2; ++i) {
    int slot = i*256 + tid, row = slot >> 3, c8 = slot & 7;
    bf16x8 v = *(const bf16x8*)(src + (long)row*NC3 + c8*8);
#pragma unroll
    for (int e = 0; e < 8; ++e) t[c8*8 + e][row] = v[e];
  }
  __syncthreads();
  bf16* dst = vt + ((long)bh*ND + dh*64)*NT + tt*64;
#pragma unroll
  for (int i = 0; i < 2; ++i) {
    int slot = i*256 + tid, row = slot >> 3, c8 = slot & 7;
    bf16x8 v = *(const bf16x8*)(&t[row][c8*8]);
    *(bf16x8*)(dst + (long)row*NT + c8*8) = v;
  }
}

// ---------------- GEMM 256x256, 8 waves, 4-phase interleave, dbuf + counted prefetch ----------------
// C[M,N] = A[M,K] * B with BT = B^T [N,K] row-major. Grid: 1-D, nwg = (N/256)*(M/256), nwg%8==0.
template <typename OT>
__global__ __launch_bounds__(512, 2) void gemm256_k(const bf16* __restrict__ A, const bf16* __restrict__ BT,
                                                    OT* __restrict__ Cout, int M, int N, int K, int nbx) {
  const int nwg = gridDim.x;
  const int bid = blockIdx.x;
  const int cpx = nwg >> 3;                     // XCD swizzle (nwg%8==0)
  const int swz = (bid & 7) * cpx + (bid >> 3);
  const int bx = swz % nbx, by = swz / nbx;
  const long m0 = (long)by << 8, n0 = (long)bx << 8;

  const int tid = threadIdx.x, w = tid >> 6, l = tid & 63, g = l >> 4, r = l & 15;
  const int wm = w >> 2, wn = w & 3;            // 2 x 4 waves; per-wave C = 128 x 64

  __shared__ __align__(16) char As[2][32768];   // [256 rows][64 k] bf16, slot-swizzled
  __shared__ __align__(16) char Bs[2][32768];

  long aoff[4], boff[4];
  int slo[4];
#pragma unroll
  for (int i = 0; i < 4; ++i) {
    int s = i*512 + tid, row = s >> 3, c = s & 7, cp = c ^ (row & 7);
    aoff[i] = (m0 + row)*(long)K + cp*8;
    boff[i] = (n0 + row)*(long)K + cp*8;
    slo[i] = (i*512 + w*64) << 4;
  }

  const f32x4 z4 = {0.f, 0.f, 0.f, 0.f};
  f32x4 acc[8][4];
#pragma unroll
  for (int i = 0; i < 8; ++i)
#pragma unroll
    for (int j = 0; j < 4; ++j) acc[i][j] = z4;

  const int nk = K >> 6;
  // prologue: stage tile 0 into buf 0
#pragma unroll
  for (int i = 0; i < 4; ++i) {
    gload16(A + aoff[i], As[0] + slo[i]);
    gload16(BT + boff[i], Bs[0] + slo[i]);
  }
  __syncthreads();

  bf16x8 af[8], bfr[4];

  for (int t = 0; t < nk; ++t) {
    const int cur = t & 1;
    const char* Ac = As[cur];
    const char* Bc = Bs[cur];

    // ---- phase 0: quadrant (qm=0, qn=0); also issue tile t+1 stage (lands by phase 3 drain) ----
#pragma unroll
    for (int mi = 0; mi < 4; ++mi)
#pragma unroll
      for (int kk = 0; kk < 2; ++kk) {
        int row = wm*128 + mi*16 + r;
        af[mi*2+kk] = *(const bf16x8*)(Ac + row*128 + (((kk*4 + g) ^ (row & 7)) << 4));
      }
#pragma unroll
    for (int ni = 0; ni < 2; ++ni)
#pragma unroll
      for (int kk = 0; kk < 2; ++kk) {
        int row = wn*64 + ni*16 + r;
        bfr[ni*2+kk] = *(const bf16x8*)(Bc + row*128 + (((kk*4 + g) ^ (row & 7)) << 4));
      }
    if (t + 1 < nk) {
      const long ko = (long)(t+1) << 6;
#pragma unroll
      for (int i = 0; i < 4; ++i) {
        gload16(A + aoff[i] + ko, As[cur^1] + slo[i]);
        gload16(BT + boff[i] + ko, Bs[cur^1] + slo[i]);
      }
    }
    __builtin_amdgcn_s_setprio(1);
#pragma unroll
    for (int mi = 0; mi < 4; ++mi)
#pragma unroll
      for (int ni = 0; ni < 2; ++ni)
#pragma unroll
        for (int kk = 0; kk < 2; ++kk)
          acc[mi][ni] = __builtin_amdgcn_mfma_f32_16x16x32_bf16(af[mi*2+kk], bfr[ni*2+kk], acc[mi][ni], 0, 0, 0);
    __builtin_amdgcn_s_setprio(0);
    __builtin_amdgcn_s_barrier();

    // ---- phase 1: quadrant (qm=1, qn=0): new A-half, keep B ----
#pragma unroll
    for (int mi = 0; mi < 4; ++mi)
#pragma unroll
      for (int kk = 0; kk < 2; ++kk) {
        int row = wm*128 + 64 + mi*16 + r;
        af[mi*2+kk] = *(const bf16x8*)(Ac + row*128 + (((kk*4 + g) ^ (row & 7)) << 4));
      }
    __builtin_amdgcn_s_setprio(1);
#pragma unroll
    for (int mi = 0; mi < 4; ++mi)
#pragma unroll
      for (int ni = 0; ni < 2; ++ni)
#pragma unroll
        for (int kk = 0; kk < 2; ++kk)
          acc[4+mi][ni] = __builtin_amdgcn_mfma_f32_16x16x32_bf16(af[mi*2+kk], bfr[ni*2+kk], acc[4+mi][ni], 0, 0, 0);
    __builtin_amdgcn_s_setprio(0);
    __builtin_amdgcn_s_barrier();

    // ---- phase 2: quadrant (qm=1, qn=1): new B-half, keep A ----
#pragma unroll
    for (int ni = 0; ni < 2; ++ni)
#pragma unroll
      for (int kk = 0; kk < 2; ++kk) {
        int row = wn*64 + 32 + ni*16 + r;
        bfr[ni*2+kk] = *(const bf16x8*)(Bc + row*128 + (((kk*4 + g) ^ (row & 7)) << 4));
      }
    __builtin_amdgcn_s_setprio(1);
#pragma unroll
    for (int mi = 0; mi < 4; ++mi)
#pragma unroll
      for (int ni = 0; ni < 2; ++ni)
#pragma unroll
        for (int kk = 0; kk < 2; ++kk)
          acc[4+mi][2+ni] = __builtin_amdgcn_mfma_f32_16x16x32_bf16(af[mi*2+kk], bfr[ni*2+kk], acc[4+mi][2+ni], 0, 0, 0);
    __builtin_amdgcn_s_setprio(0);
    __builtin_amdgcn_s_barrier();

    // ---- phase 3: quadrant (qm=0, qn=1): new A-half (qm0), keep B ----
#pragma unroll
    for (int mi = 0; mi < 4; ++mi)
#pragma unroll
      for (int kk = 0; kk < 2; ++kk) {
        int row = wm*128 + mi*16 + r;
        af[mi*2+kk] = *(const bf16x8*)(Ac + row*128 + (((kk*4 + g) ^ (row & 7)) << 4));
      }
    __builtin_amdgcn_s_setprio(1);
#pragma unroll
    for (int mi = 0; mi < 4; ++mi)
#pragma unroll
      for (int ni = 0; ni < 2; ++ni)
#pragma unroll
        for (int kk = 0; kk < 2; ++kk)
          acc[mi][2+ni] = __builtin_amdgcn_mfma_f32_16x16x32_bf16(af[mi*2+kk], bfr[ni*2+kk], acc[mi][2+ni], 0, 0, 0);
    __builtin_amdgcn_s_setprio(0);
    __syncthreads();   // vmcnt(0)+lgkmcnt(0) drain + barrier: gates tile t+1 reads & buffer reuse
  }

  // epilogue
#pragma unroll
  for (int mi = 0; mi < 8; ++mi)
#pragma unroll
    for (int ni = 0; ni < 4; ++ni)
#pragma unroll
      for (int j = 0; j < 4; ++j) {
        long mr = m0 + wm*128 + mi*16 + 4*g + j;
        long nc = n0 + wn*64 + ni*16 + r;
        Cout[mr*(long)N + nc] = (OT)acc[mi][ni][j];
      }
}

// ---------------- flash attention v10: swapped-QK in-register softmax (round-10, passing) ----------------
__global__ __launch_bounds__(256, 2) void attn_k(const bf16* __restrict__ qkv, const bf16* __restrict__ vt,
                                                 const int* __restrict__ mask, bf16* __restrict__ y) {
  const int qx = blockIdx.x, h = blockIdx.y, b = blockIdx.z;
  const int qt = (qx & 1) ? (31 - (qx >> 1)) : (qx >> 1);   // work-balance remap (bijective)
  const int tid = threadIdx.x, w = tid >> 6, l = tid & 63, g = l >> 4, r = l & 15;
  const int q0 = qt << 6;
  const int bh = b*NH + h;
  const int ntiles = qt + 1;
  const int qrow = q0 + w*16 + r;                 // this lane's q-row

  __shared__ __align__(16) char Klds[2][16384];   // [64 key][128 d], swizzled 16B slots
  __shared__ __align__(16) char Vlds[2][16384];   // [128 d][64 key], swizzled
  __shared__ __align__(16) char Plds[8192];       // per-wave [16 q][64 key] bf16, xor (r&7)<<4
  __shared__ char Mc[2048];                       // key mask (char) for this b
  char* Pl = Plds + (w << 11);

  for (int i = tid; i < q0 + 64; i += 256) Mc[i] = (char)(mask[b*NT + i] != 0);

  long koff[4], voff[4];
  int klo[4];
#pragma unroll
  for (int i = 0; i < 4; ++i) {
    int slot = i*256 + tid;                       // K: 64 rows x 16 slots
    int row = slot >> 4, c = slot & 15, cp = c ^ (row & 7);
    koff[i] = (long)row*NC3 + cp*8;
    klo[i] = (i*256 + w*64) << 4;
    int vrow = slot >> 3, vc = slot & 7, vcp = vc ^ (vrow & 7);   // VT: 128 rows x 8 slots
    voff[i] = (long)vrow*NT + vcp*8;
  }
  const bf16* kbase0 = qkv + (long)(b*NT)*NC3 + (NC + h*ND);
  const bf16* vbase0 = vt + (long)bh*ND*NT;

  bf16x8 qf[4];
  {
    const bf16* qp = qkv + (long)(b*NT + qrow)*NC3 + h*ND + g*8;
#pragma unroll
    for (int dk = 0; dk < 4; ++dk) qf[dk] = *(const bf16x8*)(qp + dk*32);
  }

  const f32x4 z4 = {0.f, 0.f, 0.f, 0.f};
  f32x4 acc[8];
#pragma unroll
  for (int i = 0; i < 8; ++i) acc[i] = z4;
  float m_run = 0.0f;   // init 0 (not -inf): fully-masked tiles then give p=exp2(-3e38-m)=0 under defer-max
  float l_run = 0.0f;

  const float SCL = 0.08838834764831845f * 1.4426950408889634f;  // 1/sqrt(128) * log2(e)

  // prologue: stage tile 0 into buffer 0
#pragma unroll
  for (int i = 0; i < 4; ++i) {
    gload16(kbase0 + koff[i], Klds[0] + klo[i]);
    gload16(vbase0 + voff[i], Vlds[0] + klo[i]);
  }
  __syncthreads();

  for (int kt = 0; kt < ntiles; ++kt) {
    const int cur = kt & 1;
    if (kt + 1 < ntiles) {
      const bf16* kb = kbase0 + (long)((kt+1)*64)*NC3;
      const bf16* vb = vbase0 + (kt+1)*64;
#pragma unroll
      for (int i = 0; i < 4; ++i) {
        gload16(kb + koff[i], Klds[cur^1] + klo[i]);
        gload16(vb + voff[i], Vlds[cur^1] + klo[i]);
      }
    }
    const char* Kl = Klds[cur];
    const char* Vl = Vlds[cur];
    const int key0 = kt*64;
    const bool act = (key0 <= q0 + w*16 + 15);     // wave-uniform causal skip

    if (act) {
      u32 mw_[4];
#pragma unroll
      for (int kc = 0; kc < 4; ++kc) mw_[kc] = *(const u32*)(Mc + key0 + kc*16 + 4*g);

      float tv[4][4];
      __builtin_amdgcn_s_setprio(1);
#pragma unroll
      for (int kc = 0; kc < 4; ++kc) {
        const int krow = kc*16 + r;
        f32x4 s = z4;
#pragma unroll
        for (int dk = 0; dk < 4; ++dk) {
          bf16x8 kf = *(const bf16x8*)(Kl + krow*256 + (((dk*4 + g) ^ (krow & 7)) << 4));
          s = __builtin_amdgcn_mfma_f32_16x16x32_bf16(kf, qf[dk], s, 0, 0, 0);  // SWAPPED
        }
#pragma unroll
        for (int j = 0; j < 4; ++j) {
          const int key = key0 + kc*16 + 4*g + j;
          const bool ok = ((mw_[kc] >> (8*j)) & 0xffu) && (key <= qrow);
          tv[kc][j] = ok ? s[j]*SCL : -3.0e38f;
        }
      }
      __builtin_amdgcn_s_setprio(0);

      // row max: in-lane 16 + 2 shfl across g
      float tmax = -3.0e38f;
#pragma unroll
      for (int kc = 0; kc < 4; ++kc)
#pragma unroll
        for (int j = 0; j < 4; ++j) tmax = fmaxf(tmax, tv[kc][j]);
      tmax = fmaxf(tmax, __shfl_xor(tmax, 16));
      tmax = fmaxf(tmax, __shfl_xor(tmax, 32));

      // defer-max (T13, THR=8 in log2 domain)
      if (!__all(tmax <= m_run + 8.0f)) {
        float mn = fmaxf(m_run, tmax);
        float al = exp2f(m_run - mn);
        m_run = mn;
        l_run *= al;
        float alj[4];
#pragma unroll
        for (int j = 0; j < 4; ++j) alj[j] = __shfl(al, 4*g + j);
#pragma unroll
        for (int d0 = 0; d0 < 8; ++d0)
#pragma unroll
          for (int j = 0; j < 4; ++j) acc[d0][j] *= alj[j];
      }

      // p = exp2(tv - m), in-lane sum, pack to bf16 pairs, write P (4x ds_write_b64)
      float rs = 0.f;
      u32 pk0[4], pk1[4];
#pragma unroll
      for (int kc = 0; kc < 4; ++kc) {
        float p0 = exp2f(tv[kc][0] - m_run), p1 = exp2f(tv[kc][1] - m_run);
        float p2 = exp2f(tv[kc][2] - m_run), p3 = exp2f(tv[kc][3] - m_run);
        rs += (p0 + p1) + (p2 + p3);
        pk0[kc] = pack_bf16(p0, p1);
        pk1[kc] = pack_bf16(p2, p3);
      }
      rs += __shfl_xor(rs, 16);
      rs += __shfl_xor(rs, 32);
      l_run += rs;
#pragma unroll
      for (int kc = 0; kc < 4; ++kc) {
        const int off = (kc*32 + g*8) ^ ((r & 7) << 4);
        uint2 wv; wv.x = pk0[kc]; wv.y = pk1[kc];
        *(uint2*)(Pl + r*128 + off) = wv;
      }
      // P write -> read fence (same-wave DS; pin hw counter + scheduler, rule #18)
      asm volatile("s_waitcnt lgkmcnt(0)" ::: "memory");
      __builtin_amdgcn_sched_barrier(0);
      bf16x8 pa[2];
#pragma unroll
      for (int kk = 0; kk < 2; ++kk)
        pa[kk] = *(const bf16x8*)(Pl + r*128 + ((kk*64 + g*16) ^ ((r & 7) << 4)));

      __builtin_amdgcn_s_setprio(1);
#pragma unroll
      for (int d0 = 0; d0 < 8; ++d0) {
        const int vrow = d0*16 + r;
#pragma unroll
        for (int kk = 0; kk < 2; ++kk) {
          bf16x8 vf = *(const bf16x8*)(Vl + vrow*128 + (((kk*4 + g) ^ (vrow & 7)) << 4));
          acc[d0] = __builtin_amdgcn_mfma_f32_16x16x32_bf16(pa[kk], vf, acc[d0], 0, 0, 0);
        }
      }
      __builtin_amdgcn_s_setprio(0);
    }
    __syncthreads();   // next-tile stage complete + guards K/V/P buffer reuse
  }

  // epilogue: normalize; acc rows are q=4g+j, l_run lives at lanes r'=4g+j
  float lr[4];
#pragma unroll
  for (int j = 0; j < 4; ++j) lr[j] = __shfl(l_run, 4*g + j);
#pragma unroll
  for (int d0 = 0; d0 < 8; ++d0)
#pragma unroll
    for (int j = 0; j < 4; ++j) {
      int qr = q0 + w*16 + 4*g + j;
      y[(long)(b*NT + qr)*NC + h*ND + d0*16 + r] = (bf16)(acc[d0][j] / lr[j]);
    }
}

extern "C" void kernel_launch(void* const* d_in, const int* in_sizes, int n_in,
                              void* d_out, int out_size, void* d_ws, size_t ws_size,
                              hipStream_t stream) {
  const float* xr     = (const float*)d_in[0];   // f32 inputs (round-6 proven)
  const void*  tok    = d_in[1];
  const float* wqkvr  = (const float*)d_in[2];
  const float* wprojr = (const float*)d_in[3];
  float* out = (float*)d_out;                    // f32 output
  char* ws = (char*)d_ws;

  bf16* qkv    = (bf16*)(ws);                       // 100,663,296 B
  bf16* yattn  = (bf16*)(ws + 100663296L);          //  33,554,432 B
  bf16* wT     = (bf16*)(ws + 134217728L);          //  25,165,824 B  W_qkv^T
  bf16* wpT    = (bf16*)(ws + 159383552L);          //   8,388,608 B  W_proj^T
  bf16* xb     = (bf16*)(ws + 167772160L);          //  33,554,432 B  bf16 x; reused as vtb
  bf16* vtb    = xb;                                //  alias: xb dead after GEMM1
  int*  maskI  = (int*)(ws + 201326592L);           //      32,768 B

  mask_prep_k<<<1, 256, 0, stream>>>(tok, maskI);
  ingest_k<<<8192, 256, 0, stream>>>(xr, xb, 16777216L);
  // fused cast+transpose of weights (f32 -> bf16, transposed)
  transpose_f32_k<<<dim3(96, 32), 256, 0, stream>>>(wqkvr, wT, NC3, NC);
  transpose_f32_k<<<dim3(32, 32), 256, 0, stream>>>(wprojr, wpT, NC, NC);
  // qkv = x @ W_qkv   (256^2 tile: grid = (6144/256)*(8192/256) = 24*32 = 768)
  gemm256_k<bf16><<<768, 512, 0, stream>>>(xb, wT, qkv, 8192, 6144, 2048, 24);
  // V^T per (b,h)  (vtb aliases xb — xb dead after GEMM1)
  vtrans_k<<<dim3(32, 2, 64), 256, 0, stream>>>(qkv, vtb);
  // attention (swapped-QK in-register softmax)
  attn_k<<<dim3(32, 16, 4), 256, 0, stream>>>(qkv, vtb, maskI, yattn);
  // out = y @ W_proj  (f32 output; grid = (2048/256)*(8192/256) = 8*32 = 256)
  gemm256_k<float><<<256, 512, 0, stream>>>(yattn, wpT, out, 8192, 2048, 2048, 8);
}